// Round 5
// baseline (5410.369 us; speedup 1.0000x reference)
//
#include <hip/hip_runtime.h>
#include <math.h>

#define NTOK   32768
#define DIMS   128
#define QST    8
#define KC     1024

#define SZ_QUANT (NTOK*DIMS)
#define SZ_CODES (NTOK*QST)
#define SZ_W     (QST*KC*DIMS)
#define OFF_CODES (SZ_QUANT)
#define OFF_LOSS  (OFF_CODES + SZ_CODES)
#define OFF_W     (OFF_LOSS + 1)
#define OFF_RM    (OFF_W + SZ_W)
#define OFF_CC    (OFF_RM + SZ_W)

// d_ws float layout: [0..15] lacc; [16..8208) wsq; [8208..8208+32768) kidx (int);
// [40976 ..) replica accumulators (rm + cc per replica)
#define WS_WSQ  16
#define WS_KIDX (16 + QST*KC)
#define WS_REP  (WS_KIDX + NTOK)
#define REPSTRIDE ((size_t)SZ_W + QST*KC)

typedef __attribute__((address_space(3))) float  lds_f;
typedef const __attribute__((address_space(1))) float gbl_f;

// Transpose w[s][k][d] -> wt[s][d][k]
__global__ void rvq_transpose(const float* __restrict__ w, float* __restrict__ wt) {
    __shared__ float tile[32][33];
    int b  = blockIdx.x;            // 8 stages * 32 ktiles * 4 dtiles = 1024
    int s  = b >> 7;
    int kt = (b >> 2) & 31;
    int dt = b & 3;
    const float* wi = w  + (size_t)s * KC * DIMS;
    float*       wo = wt + (size_t)s * KC * DIMS;
    int c  = threadIdx.x & 31;
    int r8 = threadIdx.x >> 5;
    #pragma unroll
    for (int rep = 0; rep < 4; ++rep) {
        int row = rep * 8 + r8;
        tile[row][c] = wi[(size_t)(kt * 32 + row) * DIMS + dt * 32 + c];
    }
    __syncthreads();
    #pragma unroll
    for (int rep = 0; rep < 4; ++rep) {
        int row = rep * 8 + r8;
        wo[(size_t)(dt * 32 + row) * KC + kt * 32 + c] = tile[c][row];
    }
}

// ||w||^2 per code row
__global__ void rvq_wsq(const float* __restrict__ w, float* __restrict__ wsq) {
    int row  = blockIdx.x * 4 + (threadIdx.x >> 6);
    int lane = threadIdx.x & 63;
    const float* wr = w + (size_t)row * DIMS;
    float a = wr[lane];
    float b = wr[lane + 64];
    float v = a * a + b * b;
    #pragma unroll
    for (int off = 32; off > 0; off >>= 1) v += __shfl_down(v, off, 64);
    if (lane == 0) wsq[row] = v;
}

// stage one B chunk: 8 d-rows x 512 codes (16 KB). Wave w stages row w.
__device__ __forceinline__ void stageB(const float* __restrict__ wtst,
                                       float* dst, int cp, int dbase, int t) {
    int lane = t & 63;
    int wv   = t >> 6;               // 0..7 = d-row
    const float* gp = wtst + (size_t)(dbase + wv) * KC + cp * 512 + lane * 4;
    float* lp = dst + wv * 512;      // wave-uniform base; HW adds lane*16B
    __builtin_amdgcn_global_load_lds((gbl_f*)gp,         (lds_f*)lp,         16, 0, 0);
    __builtin_amdgcn_global_load_lds((gbl_f*)(gp + 256), (lds_f*)(lp + 256), 16, 0, 0);
}

// Distance + argmin only. 64 tokens/block, 512 threads, 8 tok x 8 codes each.
__global__ __launch_bounds__(512, 4)
void rvq_dist(const float* __restrict__ rin,
              const float* __restrict__ wtst,    // [D][K] this stage
              const float* __restrict__ wsqst,   // [K]
              float* __restrict__ codes_out,
              int* __restrict__ kidx,            // [N] selected code per token
              float* __restrict__ cc0,
              float* __restrict__ ccws,
              int repmask,
              int stage)
{
    __shared__ float A[DIMS * 64];       // 32 KB, [d][tok] XOR-quad swizzled
    __shared__ float BP[2][8 * 512];     // 32 KB dbuf
    __shared__ float red_d[8 * 64];
    __shared__ int   red_k[8 * 64];

    const int t    = threadIdx.x;
    const int tg   = t & 7;              // token group (8 tokens)
    const int cgr  = t >> 3;             // code group 0..63 (8 codes)
    const int tok0 = blockIdx.x * 64;

    // stage A: 64 tok x 128 d
    #pragma unroll
    for (int q = 0; q < 4; ++q) {
        int idx = q * 512 + t;           // 2048 float4s
        int tok = idx >> 5;
        int dq  = idx & 31;
        float4 v = *reinterpret_cast<const float4*>(rin + (size_t)(tok0 + tok) * DIMS + dq * 4);
        int base = ((((tok >> 2) ^ dq) & 15) << 2) + (tok & 3);
        A[(dq * 4 + 0) * 64 + base] = v.x;
        A[(dq * 4 + 1) * 64 + base] = v.y;
        A[(dq * 4 + 2) * 64 + base] = v.z;
        A[(dq * 4 + 3) * 64 + base] = v.w;
    }
    stageB(wtst, &BP[0][0], 0, 0, t);
    __syncthreads();

    float best[8];
    int   bkst[8];
    #pragma unroll
    for (int i = 0; i < 8; ++i) { best[i] = INFINITY; bkst[i] = 0; }

    const float4* A4 = reinterpret_cast<const float4*>(A);
    int buf = 0;

    for (int cp = 0; cp < 2; ++cp) {         // 2 passes of 512 codes
        float acc[8][8];
        #pragma unroll
        for (int i = 0; i < 8; ++i)
            #pragma unroll
            for (int j = 0; j < 8; ++j) acc[i][j] = 0.0f;

        for (int dch = 0; dch < 16; ++dch) { // 16 chunks of 8 d
            if (!(cp == 1 && dch == 15)) {
                int ncp = cp, ndb = (dch + 1) * 8;
                if (ndb == 128) { ncp = cp + 1; ndb = 0; }
                stageB(wtst, &BP[buf ^ 1][0], ncp, ndb, t);
            }
            #pragma unroll
            for (int dl = 0; dl < 8; ++dl) {
                const int d  = dch * 8 + dl;
                const int dq = d >> 2;
                float4 a0 = A4[d * 16 + (((2 * tg)     ^ dq) & 15)];
                float4 a1 = A4[d * 16 + (((2 * tg + 1) ^ dq) & 15)];
                const float4* Brow = reinterpret_cast<const float4*>(&BP[buf][dl * 512]);
                float4 b0 = Brow[cgr * 2];
                float4 b1 = Brow[cgr * 2 + 1];
                const float a[8]  = {a0.x,a0.y,a0.z,a0.w, a1.x,a1.y,a1.z,a1.w};
                const float bb[8] = {b0.x,b0.y,b0.z,b0.w, b1.x,b1.y,b1.z,b1.w};
                #pragma unroll
                for (int i = 0; i < 8; ++i)
                    #pragma unroll
                    for (int j = 0; j < 8; ++j)
                        acc[i][j] = fmaf(a[i], bb[j], acc[i][j]);
            }
            __syncthreads();
            buf ^= 1;
        }
        // (buf flipped an even number of times per cp; parity handled by loop)

        float4 wq0 = *reinterpret_cast<const float4*>(wsqst + cp * 512 + cgr * 8);
        float4 wq1 = *reinterpret_cast<const float4*>(wsqst + cp * 512 + cgr * 8 + 4);
        const float wqa[8] = {wq0.x,wq0.y,wq0.z,wq0.w, wq1.x,wq1.y,wq1.z,wq1.w};
        #pragma unroll
        for (int j = 0; j < 8; ++j) {
            int code = cp * 512 + cgr * 8 + j;
            #pragma unroll
            for (int i = 0; i < 8; ++i) {
                float dist = wqa[j] - 2.0f * acc[i][j];
                if (dist < best[i]) { best[i] = dist; bkst[i] = code; }
            }
        }
    }

    // in-wave butterfly across the 8 code-groups sharing each tg
    #pragma unroll
    for (int i = 0; i < 8; ++i) {
        float bd = best[i];
        int   bk = bkst[i];
        #pragma unroll
        for (int m = 8; m < 64; m <<= 1) {
            float od = __shfl_xor(bd, m, 64);
            int   ok = __shfl_xor(bk, m, 64);
            if (od < bd || (od == bd && ok < bk)) { bd = od; bk = ok; }
        }
        best[i] = bd; bkst[i] = bk;
    }
    const int wid = t >> 6;              // 8 waves
    if ((t & 56) == 0) {
        #pragma unroll
        for (int i = 0; i < 8; ++i) {
            red_d[wid * 64 + tg * 8 + i] = best[i];
            red_k[wid * 64 + tg * 8 + i] = bkst[i];
        }
    }
    __syncthreads();

    if (t < 64) {
        float bd = red_d[t];
        int   bk = red_k[t];
        #pragma unroll
        for (int w = 1; w < 8; ++w) {
            float od = red_d[w * 64 + t];
            int   ok = red_k[w * 64 + t];
            if (od < bd || (od == bd && ok < bk)) { bd = od; bk = ok; }
        }
        kidx[tok0 + t] = bk;
        codes_out[(size_t)(tok0 + t) * QST + stage] = (float)bk;
        const int rep = blockIdx.x & repmask;
        float* ccdst = rep ? ccws + (size_t)(rep - 1) * REPSTRIDE : cc0;
        atomicAdd(ccdst + bk, 1.0f);
    }
}

// Memory-only update: rm_acc[k] += r ; rout = r - w[k]
__global__ __launch_bounds__(256)
void rvq_update(const float* __restrict__ rin,
                float* __restrict__ rout,
                const float* __restrict__ wst,     // [K][D]
                const int* __restrict__ kidx,
                float* __restrict__ rm0,
                float* __restrict__ rmws,
                int repmask)
{
    __shared__ int kb[64];
    const int t    = threadIdx.x;
    const int tok0 = blockIdx.x * 64;
    if (t < 64) kb[t] = kidx[tok0 + t];
    __syncthreads();

    const int rep = blockIdx.x & repmask;
    float* rmdst = rep ? rmws + (size_t)(rep - 1) * REPSTRIDE : rm0;

    #pragma unroll
    for (int it = 0; it < 8; ++it) {
        int idx = it * 256 + t;          // 2048 float4 items
        int tok = idx >> 5;
        int dq  = idx & 31;
        int k   = kb[tok];
        float4 rv = *reinterpret_cast<const float4*>(rin + (size_t)(tok0 + tok) * DIMS + dq * 4);
        float4 wv = *reinterpret_cast<const float4*>(wst + (size_t)k * DIMS + dq * 4);
        float* rmp = rmdst + (size_t)k * DIMS + dq * 4;
        atomicAdd(rmp + 0, rv.x);
        atomicAdd(rmp + 1, rv.y);
        atomicAdd(rmp + 2, rv.z);
        atomicAdd(rmp + 3, rv.w);
        float4 o = {rv.x - wv.x, rv.y - wv.y, rv.z - wv.z, rv.w - wv.w};
        *reinterpret_cast<float4*>(rout + (size_t)(tok0 + tok) * DIMS + dq * 4) = o;
    }
}

// quantized = x - r (in place) + commitment-loss partials
__global__ void rvq_quant_loss(const float* __restrict__ x,
                               float* __restrict__ rq,
                               float* __restrict__ loss_acc) {
    __shared__ float ws[4];
    int tid = blockIdx.x * 256 + threadIdx.x;
    float lsum = 0.0f;
    #pragma unroll
    for (int rep = 0; rep < 4; ++rep) {
        size_t q = (size_t)tid + (size_t)rep * 262144;
        float4 rv = *reinterpret_cast<float4*>(rq + q * 4);
        float4 xv = *reinterpret_cast<const float4*>(x + q * 4);
        lsum += rv.x*rv.x + rv.y*rv.y + rv.z*rv.z + rv.w*rv.w;
        float4 o = {xv.x - rv.x, xv.y - rv.y, xv.z - rv.z, xv.w - rv.w};
        *reinterpret_cast<float4*>(rq + q * 4) = o;
    }
    #pragma unroll
    for (int off = 32; off > 0; off >>= 1) lsum += __shfl_down(lsum, off, 64);
    if ((threadIdx.x & 63) == 0) ws[threadIdx.x >> 6] = lsum;
    __syncthreads();
    if (threadIdx.x == 0) atomicAdd(loss_acc, ws[0] + ws[1] + ws[2] + ws[3]);
}

__global__ void rvq_fin_cc(const float* __restrict__ cc_in,
                           float* __restrict__ cc_io,
                           const float* __restrict__ ws_cc,
                           int nrep_m1,
                           const float* __restrict__ loss_acc,
                           float* __restrict__ loss_out) {
    int i = blockIdx.x * 256 + threadIdx.x;   // 8192
    float a = cc_io[i];
    for (int r = 0; r < nrep_m1; ++r) a += ws_cc[(size_t)r * REPSTRIDE + i];
    cc_io[i] = cc_in[i] * 0.99f + (a / 32768.0f) * 0.01f;
    if (i == 0) loss_out[0] = loss_acc[0] / (float)(NTOK * DIMS);
}

__global__ void rvq_fin_rmw(const float* __restrict__ rm_in,
                            float* __restrict__ rm_io,
                            const float* __restrict__ ws_rm,
                            int nrep_m1,
                            float* __restrict__ w_out,
                            const float* __restrict__ cc_fin) {
    int i = blockIdx.x * 256 + threadIdx.x;   // 1,048,576
    float a = rm_io[i];
    for (int r = 0; r < nrep_m1; ++r) a += ws_rm[(size_t)r * REPSTRIDE + i];
    float nrm = rm_in[i] * 0.99f + (a / 32768.0f) * 0.01f;
    rm_io[i] = nrm;
    w_out[i] = nrm / (1e-10f + cc_fin[i >> 7]);
}

extern "C" void kernel_launch(void* const* d_in, const int* in_sizes, int n_in,
                              void* d_out, int out_size, void* d_ws, size_t ws_size,
                              hipStream_t stream) {
    const float* x   = (const float*)d_in[0];
    const float* w   = (const float*)d_in[1];
    const float* rm  = (const float*)d_in[2];
    const float* cc  = (const float*)d_in[3];
    float* out   = (float*)d_out;
    float* quant = out;                    // residual buffer during stages
    float* codes = out + OFF_CODES;
    float* loss  = out + OFF_LOSS;
    float* wout  = out + OFF_W;            // holds wt until rvq_fin_rmw
    float* rmout = out + OFF_RM;
    float* ccout = out + OFF_CC;
    float* wsf   = (float*)d_ws;
    float* lacc  = wsf;
    float* wsq   = wsf + WS_WSQ;
    int*   kidx  = (int*)(wsf + WS_KIDX);
    float* wt    = wout;

    int R = 1;
    if (ws_size >= (WS_REP + 3 * REPSTRIDE) * sizeof(float)) R = 4;
    else if (ws_size >= (WS_REP + 1 * REPSTRIDE) * sizeof(float)) R = 2;

    hipMemsetAsync(rmout, 0, (size_t)(SZ_W + QST * KC) * sizeof(float), stream);
    hipMemsetAsync(d_ws, 0, 16 * sizeof(float), stream);
    if (R > 1)
        hipMemsetAsync(wsf + WS_REP, 0, (size_t)(R - 1) * REPSTRIDE * sizeof(float), stream);

    rvq_transpose<<<1024, 256, 0, stream>>>(w, wt);
    rvq_wsq<<<QST * KC / 4, 256, 0, stream>>>(w, wsq);

    for (int s = 0; s < QST; ++s) {
        const float* rin = (s == 0) ? x : quant;
        rvq_dist<<<NTOK / 64, 512, 0, stream>>>(
            rin,
            wt + (size_t)s * KC * DIMS,
            wsq + (size_t)s * KC,
            codes, kidx,
            ccout + (size_t)s * KC,
            wsf + WS_REP + SZ_W + (size_t)s * KC,
            R - 1, s);
        rvq_update<<<NTOK / 64, 256, 0, stream>>>(
            rin, quant,
            w + (size_t)s * KC * DIMS,
            kidx,
            rmout + (size_t)s * KC * DIMS,
            wsf + WS_REP + (size_t)s * KC * DIMS,
            R - 1);
    }

    rvq_quant_loss<<<1024, 256, 0, stream>>>(x, quant, lacc);
    rvq_fin_cc<<<QST * KC / 256, 256, 0, stream>>>(cc, ccout, wsf + WS_REP + SZ_W, R - 1, lacc, loss);
    rvq_fin_rmw<<<SZ_W / 256, 256, 0, stream>>>(rm, rmout, wsf + WS_REP, R - 1, wout, ccout);
}

// Round 6
// 1567.045 us; speedup vs baseline: 3.4526x; 3.4526x over previous
//
#include <hip/hip_runtime.h>
#include <math.h>

#define NTOK   32768
#define DIMS   128
#define QST    8
#define KC     1024

#define SZ_QUANT (NTOK*DIMS)
#define SZ_CODES (NTOK*QST)
#define SZ_W     (QST*KC*DIMS)
#define OFF_CODES (SZ_QUANT)
#define OFF_LOSS  (OFF_CODES + SZ_CODES)
#define OFF_W     (OFF_LOSS + 1)
#define OFF_RM    (OFF_W + SZ_W)
#define OFF_CC    (OFF_RM + SZ_W)

// d_ws float layout:
//  [0..16)       lacc
//  [16..8208)    wsq  (Q*K)
//  [8208..40976) kidx (int, N)
//  [40976..42000) hist (int, K)
//  [42000..43024) cursor (int, K)
//  [43024..75792) sorted (int, N)  packed (k<<15)|tok
//  [75792.. )    rm replicas (2 x SZ_W floats)
#define WS_WSQ  16
#define WS_KIDX (WS_WSQ + QST*KC)
#define WS_HIST (WS_KIDX + NTOK)
#define WS_CUR  (WS_HIST + KC)
#define WS_SORT (WS_CUR + KC)
#define WS_RREP (WS_SORT + NTOK)

typedef __attribute__((address_space(3))) float  lds_f;
typedef const __attribute__((address_space(1))) float gbl_f;

// Transpose w[s][k][d] -> wt[s][d][k]
__global__ void rvq_transpose(const float* __restrict__ w, float* __restrict__ wt) {
    __shared__ float tile[32][33];
    int b  = blockIdx.x;            // 8 stages * 32 ktiles * 4 dtiles = 1024
    int s  = b >> 7;
    int kt = (b >> 2) & 31;
    int dt = b & 3;
    const float* wi = w  + (size_t)s * KC * DIMS;
    float*       wo = wt + (size_t)s * KC * DIMS;
    int c  = threadIdx.x & 31;
    int r8 = threadIdx.x >> 5;
    #pragma unroll
    for (int rep = 0; rep < 4; ++rep) {
        int row = rep * 8 + r8;
        tile[row][c] = wi[(size_t)(kt * 32 + row) * DIMS + dt * 32 + c];
    }
    __syncthreads();
    #pragma unroll
    for (int rep = 0; rep < 4; ++rep) {
        int row = rep * 8 + r8;
        wo[(size_t)(dt * 32 + row) * KC + kt * 32 + c] = tile[c][row];
    }
}

// ||w||^2 per code row
__global__ void rvq_wsq(const float* __restrict__ w, float* __restrict__ wsq) {
    int row  = blockIdx.x * 4 + (threadIdx.x >> 6);
    int lane = threadIdx.x & 63;
    const float* wr = w + (size_t)row * DIMS;
    float a = wr[lane];
    float b = wr[lane + 64];
    float v = a * a + b * b;
    #pragma unroll
    for (int off = 32; off > 0; off >>= 1) v += __shfl_down(v, off, 64);
    if (lane == 0) wsq[row] = v;
}

// stage one B chunk: 8 d-rows x 512 codes (16 KB). Wave w stages row w.
__device__ __forceinline__ void stageB(const float* __restrict__ wtst,
                                       float* dst, int cp, int dbase, int t) {
    int lane = t & 63;
    int wv   = t >> 6;               // 0..7 = d-row
    const float* gp = wtst + (size_t)(dbase + wv) * KC + cp * 512 + lane * 4;
    float* lp = dst + wv * 512;      // wave-uniform base; HW adds lane*16B
    __builtin_amdgcn_global_load_lds((gbl_f*)gp,         (lds_f*)lp,         16, 0, 0);
    __builtin_amdgcn_global_load_lds((gbl_f*)(gp + 256), (lds_f*)(lp + 256), 16, 0, 0);
}

// Distance + argmin. 64 tokens/block, 512 threads, 8 tok x 8 codes each.
__global__ __launch_bounds__(512, 4)
void rvq_dist(const float* __restrict__ rin,
              const float* __restrict__ wtst,    // [D][K] this stage
              const float* __restrict__ wsqst,   // [K]
              float* __restrict__ codes_out,
              int* __restrict__ kidx,
              int stage)
{
    __shared__ float A[DIMS * 64];       // 32 KB, [d][tok] XOR-quad swizzled
    __shared__ float BP[2][8 * 512];     // 32 KB dbuf
    __shared__ float red_d[8 * 64];
    __shared__ int   red_k[8 * 64];

    const int t    = threadIdx.x;
    const int tg   = t & 7;              // token group (8 tokens)
    const int cgr  = t >> 3;             // code group 0..63 (8 codes)
    const int tok0 = blockIdx.x * 64;

    #pragma unroll
    for (int q = 0; q < 4; ++q) {
        int idx = q * 512 + t;           // 2048 float4s
        int tok = idx >> 5;
        int dq  = idx & 31;
        float4 v = *reinterpret_cast<const float4*>(rin + (size_t)(tok0 + tok) * DIMS + dq * 4);
        int base = ((((tok >> 2) ^ dq) & 15) << 2) + (tok & 3);
        A[(dq * 4 + 0) * 64 + base] = v.x;
        A[(dq * 4 + 1) * 64 + base] = v.y;
        A[(dq * 4 + 2) * 64 + base] = v.z;
        A[(dq * 4 + 3) * 64 + base] = v.w;
    }
    stageB(wtst, &BP[0][0], 0, 0, t);
    __syncthreads();

    float best[8];
    int   bkst[8];
    #pragma unroll
    for (int i = 0; i < 8; ++i) { best[i] = INFINITY; bkst[i] = 0; }

    const float4* A4 = reinterpret_cast<const float4*>(A);
    int buf = 0;

    for (int cp = 0; cp < 2; ++cp) {         // 2 passes of 512 codes
        float acc[8][8];
        #pragma unroll
        for (int i = 0; i < 8; ++i)
            #pragma unroll
            for (int j = 0; j < 8; ++j) acc[i][j] = 0.0f;

        for (int dch = 0; dch < 16; ++dch) { // 16 chunks of 8 d
            if (!(cp == 1 && dch == 15)) {
                int ncp = cp, ndb = (dch + 1) * 8;
                if (ndb == 128) { ncp = cp + 1; ndb = 0; }
                stageB(wtst, &BP[buf ^ 1][0], ncp, ndb, t);
            }
            #pragma unroll
            for (int dl = 0; dl < 8; ++dl) {
                const int d  = dch * 8 + dl;
                const int dq = d >> 2;
                float4 a0 = A4[d * 16 + (((2 * tg)     ^ dq) & 15)];
                float4 a1 = A4[d * 16 + (((2 * tg + 1) ^ dq) & 15)];
                const float4* Brow = reinterpret_cast<const float4*>(&BP[buf][dl * 512]);
                float4 b0 = Brow[cgr * 2];
                float4 b1 = Brow[cgr * 2 + 1];
                const float a[8]  = {a0.x,a0.y,a0.z,a0.w, a1.x,a1.y,a1.z,a1.w};
                const float bb[8] = {b0.x,b0.y,b0.z,b0.w, b1.x,b1.y,b1.z,b1.w};
                #pragma unroll
                for (int i = 0; i < 8; ++i)
                    #pragma unroll
                    for (int j = 0; j < 8; ++j)
                        acc[i][j] = fmaf(a[i], bb[j], acc[i][j]);
            }
            __syncthreads();
            buf ^= 1;
        }

        float4 wq0 = *reinterpret_cast<const float4*>(wsqst + cp * 512 + cgr * 8);
        float4 wq1 = *reinterpret_cast<const float4*>(wsqst + cp * 512 + cgr * 8 + 4);
        const float wqa[8] = {wq0.x,wq0.y,wq0.z,wq0.w, wq1.x,wq1.y,wq1.z,wq1.w};
        #pragma unroll
        for (int j = 0; j < 8; ++j) {
            int code = cp * 512 + cgr * 8 + j;
            #pragma unroll
            for (int i = 0; i < 8; ++i) {
                float dist = wqa[j] - 2.0f * acc[i][j];
                if (dist < best[i]) { best[i] = dist; bkst[i] = code; }
            }
        }
    }

    #pragma unroll
    for (int i = 0; i < 8; ++i) {
        float bd = best[i];
        int   bk = bkst[i];
        #pragma unroll
        for (int m = 8; m < 64; m <<= 1) {
            float od = __shfl_xor(bd, m, 64);
            int   ok = __shfl_xor(bk, m, 64);
            if (od < bd || (od == bd && ok < bk)) { bd = od; bk = ok; }
        }
        best[i] = bd; bkst[i] = bk;
    }
    const int wid = t >> 6;
    if ((t & 56) == 0) {
        #pragma unroll
        for (int i = 0; i < 8; ++i) {
            red_d[wid * 64 + tg * 8 + i] = best[i];
            red_k[wid * 64 + tg * 8 + i] = bkst[i];
        }
    }
    __syncthreads();

    if (t < 64) {
        float bd = red_d[t];
        int   bk = red_k[t];
        #pragma unroll
        for (int w = 1; w < 8; ++w) {
            float od = red_d[w * 64 + t];
            int   ok = red_k[w * 64 + t];
            if (od < bd || (od == bd && ok < bk)) { bd = od; bk = ok; }
        }
        kidx[tok0 + t] = bk;
        codes_out[(size_t)(tok0 + t) * QST + stage] = (float)bk;
    }
}

// Histogram of codes: 32 blocks x 256 threads, 1024 tokens/block, LDS-privatized.
__global__ __launch_bounds__(256)
void rvq_histo(const int* __restrict__ kidx, int* __restrict__ hist) {
    __shared__ int lh[KC];
    const int t = threadIdx.x;
    #pragma unroll
    for (int rep = 0; rep < 4; ++rep) lh[rep * 256 + t] = 0;
    __syncthreads();
    int base = blockIdx.x * 1024;
    #pragma unroll
    for (int rep = 0; rep < 4; ++rep) {
        int k = kidx[base + rep * 256 + t];
        atomicAdd(&lh[k], 1);
    }
    __syncthreads();
    #pragma unroll
    for (int rep = 0; rep < 4; ++rep) {
        int bin = rep * 256 + t;
        int c = lh[bin];
        if (c) atomicAdd(&hist[bin], c);
    }
}

// Exclusive scan of hist -> cursor; also finalizes code_count for this stage.
__global__ __launch_bounds__(1024)
void rvq_scan(const int* __restrict__ hist, int* __restrict__ cursor,
              const float* __restrict__ cc_in, float* __restrict__ cc_io,
              int stage) {
    __shared__ int s[KC];
    const int t = threadIdx.x;
    int h = hist[t];
    s[t] = h;
    __syncthreads();
    for (int off = 1; off < KC; off <<= 1) {
        int v = (t >= off) ? s[t - off] : 0;
        __syncthreads();
        s[t] += v;
        __syncthreads();
    }
    cursor[t] = s[t] - h;                 // exclusive prefix
    size_t gi = (size_t)stage * KC + t;
    cc_io[gi] = cc_in[gi] * 0.99f + ((float)h / 32768.0f) * 0.01f;
}

// Rank-based counting-sort scatter: 128 blocks x 256 threads.
__global__ __launch_bounds__(256)
void rvq_scatter(const int* __restrict__ kidx, int* __restrict__ cursor,
                 int* __restrict__ sorted) {
    __shared__ int lh[KC];
    __shared__ int lb[KC];
    const int t = threadIdx.x;
    #pragma unroll
    for (int rep = 0; rep < 4; ++rep) lh[rep * 256 + t] = 0;
    __syncthreads();
    int tok = blockIdx.x * 256 + t;
    int k   = kidx[tok];
    int lr  = atomicAdd(&lh[k], 1);       // local rank within block
    __syncthreads();
    #pragma unroll
    for (int rep = 0; rep < 4; ++rep) {
        int bin = rep * 256 + t;
        int c = lh[bin];
        if (c) lb[bin] = atomicAdd(&cursor[bin], c);
    }
    __syncthreads();
    int pos = lb[k] + lr;
    sorted[pos] = (k << 15) | tok;
}

// Segmented sum over sorted tokens: 512 blocks x 128 threads, 64 tokens/chunk.
// Run-boundary atomics only: <= (K + nchunks) runs total.
__global__ __launch_bounds__(128)
void rvq_segsum(const float* __restrict__ rin,
                const int* __restrict__ sorted,
                float* __restrict__ rm0,      // rmout + stage*K*D
                float* __restrict__ repbuf,   // ws replicas (stage offset applied)
                int nrep)
{
    __shared__ int pc[64];
    const int t = threadIdx.x;
    if (t < 64) pc[t] = sorted[blockIdx.x * 64 + t];
    __syncthreads();

    int rep = (int)(blockIdx.x % (unsigned)nrep);
    float* rmt = (rep == 0) ? rm0 : repbuf + (size_t)(rep - 1) * SZ_W;

    const int d = t;                      // 0..127
    int   cur = pc[0] >> 15;
    float acc = 0.0f;
    #pragma unroll 4
    for (int i = 0; i < 64; ++i) {
        int v   = pc[i];
        int c   = v >> 15;
        int tok = v & 32767;
        float val = rin[(size_t)tok * DIMS + d];
        if (c != cur) {
            atomicAdd(rmt + (size_t)cur * DIMS + d, acc);
            acc = 0.0f;
            cur = c;
        }
        acc += val;
    }
    atomicAdd(rmt + (size_t)cur * DIMS + d, acc);
}

// Streaming update (no atomics): rout = rin - w[k]
__global__ __launch_bounds__(256)
void rvq_update(const float* __restrict__ rin,
                float* __restrict__ rout,
                const float* __restrict__ wst,
                const int* __restrict__ kidx)
{
    __shared__ int kb[64];
    const int t    = threadIdx.x;
    const int tok0 = blockIdx.x * 64;
    if (t < 64) kb[t] = kidx[tok0 + t];
    __syncthreads();
    #pragma unroll
    for (int it = 0; it < 8; ++it) {
        int idx = it * 256 + t;          // 2048 float4 items
        int tok = idx >> 5;
        int dq  = idx & 31;
        int k   = kb[tok];
        float4 rv = *reinterpret_cast<const float4*>(rin + (size_t)(tok0 + tok) * DIMS + dq * 4);
        float4 wv = *reinterpret_cast<const float4*>(wst + (size_t)k * DIMS + dq * 4);
        float4 o = {rv.x - wv.x, rv.y - wv.y, rv.z - wv.z, rv.w - wv.w};
        *reinterpret_cast<float4*>(rout + (size_t)(tok0 + tok) * DIMS + dq * 4) = o;
    }
}

// quantized = x - r (in place) + commitment-loss partials
__global__ void rvq_quant_loss(const float* __restrict__ x,
                               float* __restrict__ rq,
                               float* __restrict__ loss_acc) {
    __shared__ float ws[4];
    int tid = blockIdx.x * 256 + threadIdx.x;
    float lsum = 0.0f;
    #pragma unroll
    for (int rep = 0; rep < 4; ++rep) {
        size_t q = (size_t)tid + (size_t)rep * 262144;
        float4 rv = *reinterpret_cast<float4*>(rq + q * 4);
        float4 xv = *reinterpret_cast<const float4*>(x + q * 4);
        lsum += rv.x*rv.x + rv.y*rv.y + rv.z*rv.z + rv.w*rv.w;
        float4 o = {xv.x - rv.x, xv.y - rv.y, xv.z - rv.z, xv.w - rv.w};
        *reinterpret_cast<float4*>(rq + q * 4) = o;
    }
    #pragma unroll
    for (int off = 32; off > 0; off >>= 1) lsum += __shfl_down(lsum, off, 64);
    if ((threadIdx.x & 63) == 0) ws[threadIdx.x >> 6] = lsum;
    __syncthreads();
    if (threadIdx.x == 0) atomicAdd(loss_acc, ws[0] + ws[1] + ws[2] + ws[3]);
}

__global__ void rvq_fin_rmw(const float* __restrict__ rm_in,
                            float* __restrict__ rm_io,
                            const float* __restrict__ ws_rm,  // replicas base
                            int nrep_m1,
                            float* __restrict__ w_out,
                            const float* __restrict__ cc_fin,
                            const float* __restrict__ loss_acc,
                            float* __restrict__ loss_out) {
    int i = blockIdx.x * 256 + threadIdx.x;   // 1,048,576
    float a = rm_io[i];
    for (int r = 0; r < nrep_m1; ++r) a += ws_rm[(size_t)r * SZ_W + i];
    float nrm = rm_in[i] * 0.99f + (a / 32768.0f) * 0.01f;
    rm_io[i] = nrm;
    w_out[i] = nrm / (1e-10f + cc_fin[i >> 7]);
    if (i == 0) loss_out[0] = loss_acc[0] / (float)(NTOK * DIMS);
}

extern "C" void kernel_launch(void* const* d_in, const int* in_sizes, int n_in,
                              void* d_out, int out_size, void* d_ws, size_t ws_size,
                              hipStream_t stream) {
    const float* x   = (const float*)d_in[0];
    const float* w   = (const float*)d_in[1];
    const float* rm  = (const float*)d_in[2];
    const float* cc  = (const float*)d_in[3];
    float* out   = (float*)d_out;
    float* quant = out;                    // residual buffer during stages
    float* codes = out + OFF_CODES;
    float* loss  = out + OFF_LOSS;
    float* wout  = out + OFF_W;            // holds wt until rvq_fin_rmw
    float* rmout = out + OFF_RM;
    float* ccout = out + OFF_CC;
    float* wsf   = (float*)d_ws;
    float* lacc  = wsf;
    float* wsq   = wsf + WS_WSQ;
    int*   kidx  = (int*)(wsf + WS_KIDX);
    int*   hist  = (int*)(wsf + WS_HIST);
    int*   cursor= (int*)(wsf + WS_CUR);
    int*   sorted= (int*)(wsf + WS_SORT);
    float* repbuf= wsf + WS_RREP;
    float* wt    = wout;

    int nrep = 1;
    if (ws_size >= (size_t)(WS_RREP + 2 * SZ_W) * sizeof(float)) nrep = 3;

    hipMemsetAsync(rmout, 0, (size_t)SZ_W * sizeof(float), stream);
    hipMemsetAsync(d_ws, 0, 16 * sizeof(float), stream);
    if (nrep > 1)
        hipMemsetAsync(repbuf, 0, (size_t)2 * SZ_W * sizeof(float), stream);

    rvq_transpose<<<1024, 256, 0, stream>>>(w, wt);
    rvq_wsq<<<QST * KC / 4, 256, 0, stream>>>(w, wsq);

    for (int s = 0; s < QST; ++s) {
        const float* rin = (s == 0) ? x : quant;
        hipMemsetAsync(hist, 0, KC * sizeof(int), stream);
        rvq_dist<<<NTOK / 64, 512, 0, stream>>>(
            rin,
            wt + (size_t)s * KC * DIMS,
            wsq + (size_t)s * KC,
            codes, kidx, s);
        rvq_histo<<<32, 256, 0, stream>>>(kidx, hist);
        rvq_scan<<<1, 1024, 0, stream>>>(hist, cursor, cc, ccout, s);
        rvq_scatter<<<128, 256, 0, stream>>>(kidx, cursor, sorted);
        rvq_segsum<<<NTOK / 64, 128, 0, stream>>>(
            rin, sorted,
            rmout + (size_t)s * KC * DIMS,
            repbuf + (size_t)s * KC * DIMS,
            nrep);
        rvq_update<<<NTOK / 64, 256, 0, stream>>>(
            rin, quant,
            w + (size_t)s * KC * DIMS,
            kidx);
    }

    rvq_quant_loss<<<1024, 256, 0, stream>>>(x, quant, lacc);
    rvq_fin_rmw<<<SZ_W / 256, 256, 0, stream>>>(rm, rmout, repbuf, nrep - 1,
                                                wout, ccout, lacc, loss);
}